// Round 5
// baseline (1339.798 us; speedup 1.0000x reference)
//
#include <hip/hip_runtime.h>
#include <math.h>

#define HH 768
#define WW 768
#define NPIX (HH*WW)            // 589824
#define NRR 24
#define NCC 24
#define NCELL (NRR*NCC)         // 576
#define CTOPC 36
#define NB 2

// ws layout (float offsets)
#define OFF_WPK2   0            // 55*3*5*32 = 26400 floats: [ch][d][ky][kx*6+oc] pad 32
#define OFF_ZP     26400        // 256 floats of zeros (OOB staging target)
#define OFF_FSUM   26656        // 2*576*18 = 20736
#define OFF_BOTP   47392        // 1152
#define OFF_TMEAN  48544        // 2*36*576 = 41472
#define OFF_PVAL   90016        // 576
#define OFF_BOUNDS 90592        // 96 ints

// ---------------- Kernel 0: weight repack + bounds + zero page ----------------
__global__ void prep_kernel(const float* __restrict__ w1, const float* __restrict__ w2,
                            const float* __restrict__ w3,
                            const int* __restrict__ row_ids, const int* __restrict__ col_ids,
                            float* __restrict__ wpk2, float* __restrict__ zp,
                            int* __restrict__ bounds) {
  int t = blockIdx.x * 256 + threadIdx.x;
  if (t < 55*3*5*32) {
    int ch = t / 480; int r = t % 480;
    int d = r / 160; int r2 = r % 160;
    int ky = r2 / 32; int slot = r2 % 32;
    float v = 0.f;
    if (slot < 30) {
      int kx = slot / 6, oc = slot % 6;
      const float* wsrc = (d == 0) ? w1 : ((d == 1) ? w2 : w3);
      v = wsrc[((oc * 55 + ch) * 5 + ky) * 5 + kx];
    }
    wpk2[t] = v;
  }
  if (blockIdx.x == 1 && threadIdx.x < 256) zp[threadIdx.x] = 0.f;
  if (blockIdx.x == 0 && threadIdx.x < 48) {
    int tt = threadIdx.x;
    const int* ids = (tt < 24) ? row_ids : col_ids;
    int r = tt % 24;
    int s = HH, e = HH;
    for (int h = 0; h < HH; ++h) {
      int v = ids[h];
      if (v >= r && h < s) s = h;
      if (v >= r + 1 && h < e) e = h;
    }
    int base = (tt < 24) ? 0 : 48;
    bounds[base + r] = s;
    bounds[base + 24 + r] = e;
  }
}

// ---------------- Kernel A: merged 3-dilation 5x5 conv (18 oc) + ReLU ----------------
// 256 threads; tile 16 rows x 64 cols; thread = (row 0..15, 4-px strip 0..15).
// LDS: 28 rows x 80 floats. Quarter-wave (16 lanes) = one row, contiguous float4s.
// amdgpu_waves_per_eu(2,3): cap scheduler's occupancy TARGET at 3 waves/EU ->
// VGPR budget ~170, so acc[18][4]+sp[20] (~125 live) stays in registers.
// (launch_bounds/min-only attempts left the default target at 8 -> 64 VGPR + spill.)
__global__ __attribute__((amdgpu_flat_work_group_size(256, 256)))
           __attribute__((amdgpu_waves_per_eu(2, 3)))
void conv_kernel(
    const float* __restrict__ x, const float* __restrict__ wpk2,
    const float* __restrict__ zp,
    const float* __restrict__ b1, const float* __restrict__ b2, const float* __restrict__ b3,
    float* __restrict__ out) {
  __shared__ __align__(16) float tile[2][28*80];   // 17.9 KB
  const int tid = threadIdx.x;
  const int b  = blockIdx.z;
  const int h0 = blockIdx.y * 16;
  const int w0 = blockIdx.x * 64;
  const float* xb = x + (size_t)b * 55 * NPIX;

  auto STAGE = [&](int bufi, int ch) {
    const float* xc = xb + (size_t)ch * NPIX;
    #pragma unroll
    for (int k = 0; k < 3; ++k) {
      int idx = k*256 + tid;                 // float4-chunk index, 560 total
      if (idx < 560) {
        int row = idx / 20, cc = (idx % 20) * 4;
        int gh = h0 - 6 + row, gw = w0 - 8 + cc;
        bool ok = (gh >= 0) & (gh < 768) & (gw >= 0) & (gw + 3 < 768);
        const float* src = ok ? (xc + gh*768 + gw) : (zp + (tid & 63)*4);
        float* dst = (float*)&tile[bufi][(k*256 + (tid & ~63))*4];  // wave-uniform base
        __builtin_amdgcn_global_load_lds(
            (const __attribute__((address_space(1))) void*)src,
            (__attribute__((address_space(3))) void*)dst, 16, 0, 0);
      }
    }
  };

  float acc[18][4];
  #pragma unroll
  for (int i = 0; i < 18; ++i)
    #pragma unroll
    for (int p = 0; p < 4; ++p) acc[i][p] = 0.f;

  const int r = tid >> 4;          // output row 0..15
  const int c = tid & 15;          // 4-px strip 0..15  (16 lanes/row -> contiguous reads)

#define TAPS(D, KY, BASE) \
  { const float* wr = wch + ((D-1)*5 + (KY))*32; \
    _Pragma("unroll") for (int kx = 0; kx < 5; ++kx) { \
      _Pragma("unroll") for (int oc = 0; oc < 6; ++oc) { \
        const float wv = wr[kx*6+oc]; \
        _Pragma("unroll") for (int p = 0; p < 4; ++p) \
          acc[(D-1)*6+oc][p] += sp[(BASE) + p + (kx-2)*(D)] * wv; } } }

  // wide: 5 chunks from chunk (c+0)  -> floats [4c, 4c+20)   : tap base 8
  // med : 3 chunks from chunk (c+1)  -> floats [4c+4, 4c+16) : tap base 4
#define LOADW(O) { const float4* rp = (const float4*)&tb[(r + 6 + (O))*80] + c; \
    *(float4*)&sp[0]  = rp[0]; *(float4*)&sp[4]  = rp[1]; *(float4*)&sp[8] = rp[2]; \
    *(float4*)&sp[12] = rp[3]; *(float4*)&sp[16] = rp[4]; }
#define LOADM(O) { const float4* rp = (const float4*)&tb[(r + 6 + (O))*80] + c + 1; \
    *(float4*)&sp[0] = rp[0]; *(float4*)&sp[4] = rp[1]; *(float4*)&sp[8] = rp[2]; }

  STAGE(0, 0);
  __syncthreads();
  int buf = 0;
  for (int ch = 0; ch < 55; ++ch) {
    if (ch < 54) STAGE(buf ^ 1, ch + 1);
    const float* tb = &tile[buf][0];
    const float* wch = wpk2 + ch * 480;
    float sp[20];
    LOADW(-6); TAPS(3,0,8)
    LOADM(-4); TAPS(2,0,4)
    LOADW(-3); TAPS(3,1,8)
    LOADM(-2); TAPS(1,0,4) TAPS(2,1,4)
    LOADM(-1); TAPS(1,1,4)
    LOADW( 0); TAPS(1,2,8) TAPS(2,2,8) TAPS(3,2,8)
    LOADM( 1); TAPS(1,3,4)
    LOADM( 2); TAPS(1,4,4) TAPS(2,3,4)
    LOADW( 3); TAPS(3,3,8)
    LOADM( 4); TAPS(2,4,4)
    LOADW( 6); TAPS(3,4,8)
    __syncthreads();
    buf ^= 1;
  }
#undef TAPS
#undef LOADW
#undef LOADM

  const int gr = h0 + r, gcol = w0 + c*4;
  #pragma unroll
  for (int d = 0; d < 3; ++d) {
    const float* bp = (d == 0) ? b1 : ((d == 1) ? b2 : b3);
    #pragma unroll
    for (int oc = 0; oc < 6; ++oc) {
      const float bias = bp[oc];
      float4 v;
      v.x = fmaxf(acc[d*6+oc][0] + bias, 0.f);
      v.y = fmaxf(acc[d*6+oc][1] + bias, 0.f);
      v.z = fmaxf(acc[d*6+oc][2] + bias, 0.f);
      v.w = fmaxf(acc[d*6+oc][3] + bias, 0.f);
      *(float4*)(out + ((size_t)(b*55 + 36 + d*6 + oc))*NPIX + gr*768 + gcol) = v;
    }
  }
}

// ---------------- Kernel B: per-cell sums of features + sigmoid(bot) ----------------
__global__ __launch_bounds__(256) void cellsum_kernel(const float* __restrict__ dout,
    const int* __restrict__ bounds,
    const float* __restrict__ w_bot, const float* __restrict__ b_bot,
    float* __restrict__ feat_sums, float* __restrict__ bot_partial) {
  int blk = blockIdx.x;                       // b*576 + r*24 + c
  int b = blk / NCELL; int rc = blk % NCELL; int r = rc / NCC, c = rc % NCC;
  int rs = bounds[r], re = bounds[24 + r], cs = bounds[48 + c], ce = bounds[72 + c];
  int cw = ce - cs;
  int npix = (re - rs) * cw;
  float facc[18];
  #pragma unroll
  for (int k = 0; k < 18; ++k) facc[k] = 0.f;
  float sacc = 0.f;
  float wb[18];
  #pragma unroll
  for (int k = 0; k < 18; ++k) wb[k] = w_bot[k];
  float bb = b_bot[0];
  const float* fb = dout + ((size_t)b * 55 + 36) * NPIX;
  for (int i = threadIdx.x; i < npix; i += 256) {
    int hh = rs + i / cw, ww = cs + i % cw;
    int pix = hh * WW + ww;
    float dot = bb;
    #pragma unroll
    for (int k = 0; k < 18; ++k) {
      float v = fb[(size_t)k * NPIX + pix];
      facc[k] += v;
      dot += wb[k] * v;
    }
    sacc += 1.f / (1.f + expf(-dot));
  }
  #pragma unroll
  for (int k = 0; k < 18; ++k) {
    #pragma unroll
    for (int off = 32; off; off >>= 1) facc[k] += __shfl_xor(facc[k], off);
  }
  #pragma unroll
  for (int off = 32; off; off >>= 1) sacc += __shfl_xor(sacc, off);
  __shared__ float red[4][19];
  int wv = threadIdx.x >> 6, ln = threadIdx.x & 63;
  if (ln == 0) {
    #pragma unroll
    for (int k = 0; k < 18; ++k) red[wv][k] = facc[k];
    red[wv][18] = sacc;
  }
  __syncthreads();
  if (threadIdx.x < 19) {
    float s = red[0][threadIdx.x] + red[1][threadIdx.x] + red[2][threadIdx.x] + red[3][threadIdx.x];
    if (threadIdx.x < 18) feat_sums[(size_t)blk * 18 + threadIdx.x] = s;
    else bot_partial[blk] = s;
  }
}

// ---------------- Kernel C: cell means (top) + pools ----------------
__global__ void cellmean_kernel(const float* __restrict__ feat_sums,
    const float* __restrict__ bot_partial, const int* __restrict__ bounds,
    const float* __restrict__ w_top, const float* __restrict__ b_top,
    float* __restrict__ top_means, float* __restrict__ pools_val, float* __restrict__ dout) {
  int t = blockIdx.x * 256 + threadIdx.x;
  if (t < NB * CTOPC * NCELL) {
    int c = t % NCC, r = (t / NCC) % NRR, k = (t / NCELL) % CTOPC, b = t / (NCELL * CTOPC);
    int cnt = (bounds[24 + r] - bounds[r]) * (bounds[72 + c] - bounds[48 + c]);
    float v = 0.f;
    if (cnt > 0) {
      const float* fs = feat_sums + ((size_t)(b * NCELL + r * NCC + c)) * 18;
      float dot = 0.f;
      #pragma unroll
      for (int i = 0; i < 18; ++i) dot += w_top[k * 18 + i] * fs[i];
      v = dot / (float)cnt + b_top[k];
    }
    top_means[t] = v;   // [b][k][r][c]
  }
  int t2 = t - NB * CTOPC * NCELL;
  if (t2 >= 0 && t2 < NCELL) {
    int r = t2 / NCC, c = t2 % NCC;
    int cnt = (bounds[24 + r] - bounds[r]) * (bounds[72 + c] - bounds[48 + c]);
    if (cnt < 1) cnt = 1;
    float v = (bot_partial[t2] + bot_partial[NCELL + t2]) / (2.f * (float)cnt);
    pools_val[t2] = v;
    dout[(size_t)NB * 55 * NPIX + t2] = v;           // pools b=0
    dout[(size_t)NB * 55 * NPIX + NCELL + t2] = v;   // pools b=1
  }
}

// ---------------- Kernel D: broadcast top means + bottom value ----------------
__global__ __launch_bounds__(256) void bcast_kernel(const float* __restrict__ top_means,
    const float* __restrict__ pools_val, const int* __restrict__ row_ids,
    const int* __restrict__ col_ids, float* __restrict__ out) {
  int w = blockIdx.x * 256 + threadIdx.x;
  int h = blockIdx.y;
  int b = blockIdx.z;
  int r = row_ids[h], c = col_ids[w];
  int pix = h * 768 + w;
  float* ob = out + (size_t)b * 55 * NPIX + pix;
  const float* tm = top_means + (size_t)b * CTOPC * NCELL + r * NCC + c;
  #pragma unroll
  for (int k = 0; k < 36; ++k) ob[(size_t)k * NPIX] = tm[(size_t)k * NCELL];
  ob[(size_t)54 * NPIX] = pools_val[r * NCC + c];
}

extern "C" void kernel_launch(void* const* d_in, const int* in_sizes, int n_in,
                              void* d_out, int out_size, void* d_ws, size_t ws_size,
                              hipStream_t stream) {
  const float* x      = (const float*)d_in[0];
  const int* row_ids  = (const int*)d_in[1];
  const int* col_ids  = (const int*)d_in[2];
  const float* w1     = (const float*)d_in[5];
  const float* b1     = (const float*)d_in[6];
  const float* w2     = (const float*)d_in[7];
  const float* b2     = (const float*)d_in[8];
  const float* w3     = (const float*)d_in[9];
  const float* b3     = (const float*)d_in[10];
  const float* w_top  = (const float*)d_in[11];
  const float* b_top  = (const float*)d_in[12];
  const float* w_bot  = (const float*)d_in[13];
  const float* b_bot  = (const float*)d_in[14];
  float* out = (float*)d_out;
  float* ws  = (float*)d_ws;

  float* wpk2       = ws + OFF_WPK2;
  float* zp         = ws + OFF_ZP;
  float* feat_sums  = ws + OFF_FSUM;
  float* bot_partial= ws + OFF_BOTP;
  float* top_means  = ws + OFF_TMEAN;
  float* pools_val  = ws + OFF_PVAL;
  int*   bounds     = (int*)(ws + OFF_BOUNDS);

  hipLaunchKernelGGL(prep_kernel, dim3(104), dim3(256), 0, stream,
                     w1, w2, w3, row_ids, col_ids, wpk2, zp, bounds);
  hipLaunchKernelGGL(conv_kernel, dim3(12, 48, 2), dim3(256), 0, stream,
                     x, wpk2, zp, b1, b2, b3, out);
  hipLaunchKernelGGL(cellsum_kernel, dim3(NB * NCELL), dim3(256), 0, stream,
                     out, bounds, w_bot, b_bot, feat_sums, bot_partial);
  hipLaunchKernelGGL(cellmean_kernel, dim3(165), dim3(256), 0, stream,
                     feat_sums, bot_partial, bounds, w_top, b_top, top_means, pools_val, out);
  hipLaunchKernelGGL(bcast_kernel, dim3(3, 768, 2), dim3(256), 0, stream,
                     top_means, pools_val, row_ids, col_ids, out);
}

// Round 6
// 804.358 us; speedup vs baseline: 1.6657x; 1.6657x over previous
//
#include <hip/hip_runtime.h>
#include <math.h>

#define HH 768
#define WW 768
#define NPIX (HH*WW)            // 589824
#define NRR 24
#define NCC 24
#define NCELL (NRR*NCC)         // 576
#define CTOPC 36
#define NB 2

// ws layout (float offsets)
#define OFF_WPK2   0            // 56*3*5*32 = 26880 floats: [ch][d][ky][kx*6+oc], ch55 = zeros
#define OFF_ZP     26880        // 256 floats of zeros (OOB staging target)
#define OFF_FSUM   27136        // 2*576*18 = 20736
#define OFF_BOTP   47872        // 1152
#define OFF_TMEAN  49024        // 2*36*576 = 41472
#define OFF_PVAL   90496        // 576
#define OFF_BOUNDS 91072        // 96 ints

// ---------------- Kernel 0: weight repack + bounds + zero page ----------------
__global__ void prep_kernel(const float* __restrict__ w1, const float* __restrict__ w2,
                            const float* __restrict__ w3,
                            const int* __restrict__ row_ids, const int* __restrict__ col_ids,
                            float* __restrict__ wpk2, float* __restrict__ zp,
                            int* __restrict__ bounds) {
  int t = blockIdx.x * 256 + threadIdx.x;
  if (t < 56*480) {
    int ch = t / 480; int r = t % 480;
    int d = r / 160; int r2 = r % 160;
    int ky = r2 / 32; int slot = r2 % 32;
    float v = 0.f;
    if (slot < 30 && ch < 55) {
      int kx = slot / 6, oc = slot % 6;
      const float* wsrc = (d == 0) ? w1 : ((d == 1) ? w2 : w3);
      v = wsrc[((oc * 55 + ch) * 5 + ky) * 5 + kx];
    }
    wpk2[t] = v;
  }
  if (blockIdx.x == 1 && threadIdx.x < 256) zp[threadIdx.x] = 0.f;
  if (blockIdx.x == 0 && threadIdx.x < 48) {
    int tt = threadIdx.x;
    const int* ids = (tt < 24) ? row_ids : col_ids;
    int r = tt % 24;
    int s = HH, e = HH;
    for (int h = 0; h < HH; ++h) {
      int v = ids[h];
      if (v >= r && h < s) s = h;
      if (v >= r + 1 && h < e) e = h;
    }
    int base = (tt < 24) ? 0 : 48;
    bounds[base + r] = s;
    bounds[base + 24 + r] = e;
  }
}

// ---------------- Kernel A: merged 3-dilation 5x5 conv (18 oc) + ReLU ----------------
// 256 threads; tile 16 rows x 64 cols; thread = (row 0..15, 4-px strip 0..15).
// 2 channels per phase (28 phases, 28 barriers), double-buffered -> 35.8 KB LDS,
// 4 blocks/CU resident for cross-block latency hiding of the barrier drain.
// waves_per_eu(2,4): VGPR cap 128 (need ~92-110) -> no spill, 4 waves/SIMD.
__global__ __attribute__((amdgpu_flat_work_group_size(256, 256)))
           __attribute__((amdgpu_waves_per_eu(2, 4)))
void conv_kernel(
    const float* __restrict__ x, const float* __restrict__ wpk2,
    const float* __restrict__ zp,
    const float* __restrict__ b1, const float* __restrict__ b2, const float* __restrict__ b3,
    float* __restrict__ out) {
  __shared__ __align__(16) float tile[2][2][28*80];   // 35.8 KB
  const int tid = threadIdx.x;
  const int b  = blockIdx.z;
  const int h0 = blockIdx.y * 16;
  const int w0 = blockIdx.x * 64;
  const float* xb = x + (size_t)b * 55 * NPIX;

  auto STAGE = [&](int bufi, int sub, int ch) {
    const float* xc = xb + (size_t)ch * NPIX;
    const bool real = (ch < 55);
    #pragma unroll
    for (int k = 0; k < 3; ++k) {
      int idx = k*256 + tid;                 // float4-chunk index, 560 total
      if (idx < 560) {
        int row = idx / 20, cc = (idx % 20) * 4;
        int gh = h0 - 6 + row, gw = w0 - 8 + cc;
        bool ok = real & (gh >= 0) & (gh < 768) & (gw >= 0) & (gw + 3 < 768);
        const float* src = ok ? (xc + gh*768 + gw) : (zp + (tid & 63)*4);
        float* dst = (float*)&tile[bufi][sub][(k*256 + (tid & ~63))*4];  // wave-uniform base
        __builtin_amdgcn_global_load_lds(
            (const __attribute__((address_space(1))) void*)src,
            (__attribute__((address_space(3))) void*)dst, 16, 0, 0);
      }
    }
  };

  float acc[18][4];
  #pragma unroll
  for (int i = 0; i < 18; ++i)
    #pragma unroll
    for (int p = 0; p < 4; ++p) acc[i][p] = 0.f;

  const int r = tid >> 4;          // output row 0..15
  const int c = tid & 15;          // 4-px strip 0..15  (16 lanes/row -> contiguous reads)

#define TAPS(D, KY, BASE) \
  { const float* wr = wch + ((D-1)*5 + (KY))*32; \
    _Pragma("unroll") for (int kx = 0; kx < 5; ++kx) { \
      _Pragma("unroll") for (int oc = 0; oc < 6; ++oc) { \
        const float wv = wr[kx*6+oc]; \
        _Pragma("unroll") for (int p = 0; p < 4; ++p) \
          acc[(D-1)*6+oc][p] += sp[(BASE) + p + (kx-2)*(D)] * wv; } } }

  // wide: 5 chunks from chunk (c+0)  -> floats [4c, 4c+20)   : tap base 8
  // med : 3 chunks from chunk (c+1)  -> floats [4c+4, 4c+16) : tap base 4
#define LOADW(O) { const float4* rp = (const float4*)&tb[(r + 6 + (O))*80] + c; \
    *(float4*)&sp[0]  = rp[0]; *(float4*)&sp[4]  = rp[1]; *(float4*)&sp[8] = rp[2]; \
    *(float4*)&sp[12] = rp[3]; *(float4*)&sp[16] = rp[4]; }
#define LOADM(O) { const float4* rp = (const float4*)&tb[(r + 6 + (O))*80] + c + 1; \
    *(float4*)&sp[0] = rp[0]; *(float4*)&sp[4] = rp[1]; *(float4*)&sp[8] = rp[2]; }

  STAGE(0, 0, 0);
  STAGE(0, 1, 1);
  __syncthreads();
  int buf = 0;
  for (int p2 = 0; p2 < 28; ++p2) {
    const int chbase = 2*p2;
    if (p2 < 27) { STAGE(buf ^ 1, 0, chbase + 2); STAGE(buf ^ 1, 1, chbase + 3); }
    #pragma unroll
    for (int s = 0; s < 2; ++s) {
      const float* tb = &tile[buf][s][0];
      const float* wch = wpk2 + (chbase + s) * 480;
      float sp[20];
      LOADW(-6); TAPS(3,0,8)
      LOADM(-4); TAPS(2,0,4)
      LOADW(-3); TAPS(3,1,8)
      LOADM(-2); TAPS(1,0,4) TAPS(2,1,4)
      LOADM(-1); TAPS(1,1,4)
      LOADW( 0); TAPS(1,2,8) TAPS(2,2,8) TAPS(3,2,8)
      LOADM( 1); TAPS(1,3,4)
      LOADM( 2); TAPS(1,4,4) TAPS(2,3,4)
      LOADW( 3); TAPS(3,3,8)
      LOADM( 4); TAPS(2,4,4)
      LOADW( 6); TAPS(3,4,8)
    }
    __syncthreads();
    buf ^= 1;
  }
#undef TAPS
#undef LOADW
#undef LOADM

  const int gr = h0 + r, gcol = w0 + c*4;
  #pragma unroll
  for (int d = 0; d < 3; ++d) {
    const float* bp = (d == 0) ? b1 : ((d == 1) ? b2 : b3);
    #pragma unroll
    for (int oc = 0; oc < 6; ++oc) {
      const float bias = bp[oc];
      float4 v;
      v.x = fmaxf(acc[d*6+oc][0] + bias, 0.f);
      v.y = fmaxf(acc[d*6+oc][1] + bias, 0.f);
      v.z = fmaxf(acc[d*6+oc][2] + bias, 0.f);
      v.w = fmaxf(acc[d*6+oc][3] + bias, 0.f);
      *(float4*)(out + ((size_t)(b*55 + 36 + d*6 + oc))*NPIX + gr*768 + gcol) = v;
    }
  }
}

// ---------------- Kernel B: per-cell sums of features + sigmoid(bot) ----------------
__global__ __launch_bounds__(256) void cellsum_kernel(const float* __restrict__ dout,
    const int* __restrict__ bounds,
    const float* __restrict__ w_bot, const float* __restrict__ b_bot,
    float* __restrict__ feat_sums, float* __restrict__ bot_partial) {
  int blk = blockIdx.x;                       // b*576 + r*24 + c
  int b = blk / NCELL; int rc = blk % NCELL; int r = rc / NCC, c = rc % NCC;
  int rs = bounds[r], re = bounds[24 + r], cs = bounds[48 + c], ce = bounds[72 + c];
  int cw = ce - cs;
  int npix = (re - rs) * cw;
  float facc[18];
  #pragma unroll
  for (int k = 0; k < 18; ++k) facc[k] = 0.f;
  float sacc = 0.f;
  float wb[18];
  #pragma unroll
  for (int k = 0; k < 18; ++k) wb[k] = w_bot[k];
  float bb = b_bot[0];
  const float* fb = dout + ((size_t)b * 55 + 36) * NPIX;
  for (int i = threadIdx.x; i < npix; i += 256) {
    int hh = rs + i / cw, ww = cs + i % cw;
    int pix = hh * WW + ww;
    float dot = bb;
    #pragma unroll
    for (int k = 0; k < 18; ++k) {
      float v = fb[(size_t)k * NPIX + pix];
      facc[k] += v;
      dot += wb[k] * v;
    }
    sacc += 1.f / (1.f + expf(-dot));
  }
  #pragma unroll
  for (int k = 0; k < 18; ++k) {
    #pragma unroll
    for (int off = 32; off; off >>= 1) facc[k] += __shfl_xor(facc[k], off);
  }
  #pragma unroll
  for (int off = 32; off; off >>= 1) sacc += __shfl_xor(sacc, off);
  __shared__ float red[4][19];
  int wv = threadIdx.x >> 6, ln = threadIdx.x & 63;
  if (ln == 0) {
    #pragma unroll
    for (int k = 0; k < 18; ++k) red[wv][k] = facc[k];
    red[wv][18] = sacc;
  }
  __syncthreads();
  if (threadIdx.x < 19) {
    float s = red[0][threadIdx.x] + red[1][threadIdx.x] + red[2][threadIdx.x] + red[3][threadIdx.x];
    if (threadIdx.x < 18) feat_sums[(size_t)blk * 18 + threadIdx.x] = s;
    else bot_partial[blk] = s;
  }
}

// ---------------- Kernel C: cell means (top) + pools ----------------
__global__ void cellmean_kernel(const float* __restrict__ feat_sums,
    const float* __restrict__ bot_partial, const int* __restrict__ bounds,
    const float* __restrict__ w_top, const float* __restrict__ b_top,
    float* __restrict__ top_means, float* __restrict__ pools_val, float* __restrict__ dout) {
  int t = blockIdx.x * 256 + threadIdx.x;
  if (t < NB * CTOPC * NCELL) {
    int c = t % NCC, r = (t / NCC) % NRR, k = (t / NCELL) % CTOPC, b = t / (NCELL * CTOPC);
    int cnt = (bounds[24 + r] - bounds[r]) * (bounds[72 + c] - bounds[48 + c]);
    float v = 0.f;
    if (cnt > 0) {
      const float* fs = feat_sums + ((size_t)(b * NCELL + r * NCC + c)) * 18;
      float dot = 0.f;
      #pragma unroll
      for (int i = 0; i < 18; ++i) dot += w_top[k * 18 + i] * fs[i];
      v = dot / (float)cnt + b_top[k];
    }
    top_means[t] = v;   // [b][k][r][c]
  }
  int t2 = t - NB * CTOPC * NCELL;
  if (t2 >= 0 && t2 < NCELL) {
    int r = t2 / NCC, c = t2 % NCC;
    int cnt = (bounds[24 + r] - bounds[r]) * (bounds[72 + c] - bounds[48 + c]);
    if (cnt < 1) cnt = 1;
    float v = (bot_partial[t2] + bot_partial[NCELL + t2]) / (2.f * (float)cnt);
    pools_val[t2] = v;
    dout[(size_t)NB * 55 * NPIX + t2] = v;           // pools b=0
    dout[(size_t)NB * 55 * NPIX + NCELL + t2] = v;   // pools b=1
  }
}

// ---------------- Kernel D: broadcast top means + bottom value ----------------
__global__ __launch_bounds__(256) void bcast_kernel(const float* __restrict__ top_means,
    const float* __restrict__ pools_val, const int* __restrict__ row_ids,
    const int* __restrict__ col_ids, float* __restrict__ out) {
  int w = blockIdx.x * 256 + threadIdx.x;
  int h = blockIdx.y;
  int b = blockIdx.z;
  int r = row_ids[h], c = col_ids[w];
  int pix = h * 768 + w;
  float* ob = out + (size_t)b * 55 * NPIX + pix;
  const float* tm = top_means + (size_t)b * CTOPC * NCELL + r * NCC + c;
  #pragma unroll
  for (int k = 0; k < 36; ++k) ob[(size_t)k * NPIX] = tm[(size_t)k * NCELL];
  ob[(size_t)54 * NPIX] = pools_val[r * NCC + c];
}

extern "C" void kernel_launch(void* const* d_in, const int* in_sizes, int n_in,
                              void* d_out, int out_size, void* d_ws, size_t ws_size,
                              hipStream_t stream) {
  const float* x      = (const float*)d_in[0];
  const int* row_ids  = (const int*)d_in[1];
  const int* col_ids  = (const int*)d_in[2];
  const float* w1     = (const float*)d_in[5];
  const float* b1     = (const float*)d_in[6];
  const float* w2     = (const float*)d_in[7];
  const float* b2     = (const float*)d_in[8];
  const float* w3     = (const float*)d_in[9];
  const float* b3     = (const float*)d_in[10];
  const float* w_top  = (const float*)d_in[11];
  const float* b_top  = (const float*)d_in[12];
  const float* w_bot  = (const float*)d_in[13];
  const float* b_bot  = (const float*)d_in[14];
  float* out = (float*)d_out;
  float* ws  = (float*)d_ws;

  float* wpk2       = ws + OFF_WPK2;
  float* zp         = ws + OFF_ZP;
  float* feat_sums  = ws + OFF_FSUM;
  float* bot_partial= ws + OFF_BOTP;
  float* top_means  = ws + OFF_TMEAN;
  float* pools_val  = ws + OFF_PVAL;
  int*   bounds     = (int*)(ws + OFF_BOUNDS);

  hipLaunchKernelGGL(prep_kernel, dim3(105), dim3(256), 0, stream,
                     w1, w2, w3, row_ids, col_ids, wpk2, zp, bounds);
  hipLaunchKernelGGL(conv_kernel, dim3(12, 48, 2), dim3(256), 0, stream,
                     x, wpk2, zp, b1, b2, b3, out);
  hipLaunchKernelGGL(cellsum_kernel, dim3(NB * NCELL), dim3(256), 0, stream,
                     out, bounds, w_bot, b_bot, feat_sums, bot_partial);
  hipLaunchKernelGGL(cellmean_kernel, dim3(165), dim3(256), 0, stream,
                     feat_sums, bot_partial, bounds, w_top, b_top, top_means, pools_val, out);
  hipLaunchKernelGGL(bcast_kernel, dim3(3, 768, 2), dim3(256), 0, stream,
                     top_means, pools_val, row_ids, col_ids, out);
}